// Round 12
// baseline (229.237 us; speedup 1.0000x reference)
//
#include <hip/hip_runtime.h>
#include <hip/hip_bf16.h>
#include <stdint.h>

// Problem constants
#define B_   2
#define T_   2048
#define D_   1024
#define H_   16
#define HD_  64
#define MEM_ 512
#define KV_  (MEM_ + T_)   // 2560
#define NIT_ (KV_ / 64)    // 40 kv-tiles of 64
#define HITER (NIT_ / 2)   // 20 per half

#define XN_   (4096 * 1024)   // x elems
#define WQN_  (3072 * 1024)   // w_qkv elems
#define WON_  (1024 * 1024)   // w_out elems

using bf16 = __bf16;
typedef __bf16 bf16x8 __attribute__((ext_vector_type(8)));
typedef float  f32x4  __attribute__((ext_vector_type(4)));
typedef short  s16x4  __attribute__((ext_vector_type(4)));

__device__ __forceinline__ f32x4 mfma16(bf16x8 a, bf16x8 b, f32x4 c) {
  return __builtin_amdgcn_mfma_f32_16x16x32_bf16(a, b, c, 0, 0, 0);
}
__device__ __forceinline__ f32x4 mfma16k16(s16x4 a, s16x4 b, f32x4 c) {
  return __builtin_amdgcn_mfma_f32_16x16x16bf16_1k(a, b, c, 0, 0, 0);
}

// async global->LDS DMA, 16B/lane; LDS dest = wave-uniform base + lane*16
__device__ __forceinline__ void gl_lds16(const bf16* g, bf16* l) {
  __builtin_amdgcn_global_load_lds(
      (const __attribute__((address_space(1))) void*)g,
      (__attribute__((address_space(3))) void*)l, 16, 0, 0);
}

__device__ __forceinline__ unsigned short bf16_bits(float f) {
  bf16 h = (bf16)f;
  return __builtin_bit_cast(unsigned short, h);
}

__device__ __forceinline__ ushort4 pack4(f32x4 v) {
  ushort4 p;
  p.x = bf16_bits(v[0]); p.y = bf16_bits(v[1]);
  p.z = bf16_bits(v[2]); p.w = bf16_bits(v[3]);
  return p;
}

// ---------------------------------------------------------------------------
// convert_all: f32 -> bf16 for x, w_qkv, w_out; memory -> mem_k + mem_vt.
// ---------------------------------------------------------------------------
__global__ void convert_all(const float* __restrict__ x,
                            const float* __restrict__ wq,
                            const float* __restrict__ wo,
                            const float* __restrict__ mem,
                            bf16* __restrict__ xb, bf16* __restrict__ wqb,
                            bf16* __restrict__ wob, bf16* __restrict__ mem_k,
                            bf16* __restrict__ mem_vt) {
  size_t e = ((size_t)blockIdx.x * 256 + threadIdx.x) * 4;
  if (e < XN_) {
    f32x4 v = *(const f32x4*)(x + e);
    *(ushort4*)&xb[e] = pack4(v);
  } else if (e < XN_ + WQN_) {
    size_t o = e - XN_;
    f32x4 v = *(const f32x4*)(wq + o);
    *(ushort4*)&wqb[o] = pack4(v);
  } else if (e < XN_ + WQN_ + WON_) {
    size_t o = e - XN_ - WQN_;
    f32x4 v = *(const f32x4*)(wo + o);
    *(ushort4*)&wob[o] = pack4(v);
  } else {
    size_t o = e - XN_ - WQN_ - WON_;
    f32x4 v = *(const f32x4*)(mem + o);
    *(ushort4*)&mem_k[o] = pack4(v);
    int m = (int)(o >> 10), d = (int)(o & 1023);
#pragma unroll
    for (int j = 0; j < 4; j++)
      mem_vt[(size_t)(d + j) * MEM_ + m] = (bf16)v[j];
  }
}

// ---------------------------------------------------------------------------
// GEMM (B^T form): C[M,N] = A[M,K] * W[N,K]^T.  128x128 tile, BK=32,
// 4 waves (2x2 of 64x64).  bf16 operands, global_load_lds width-16 staging.
// EPI==0: scatter q/k -> [bh][t][64], v -> vt_ws[bh][hd][t] (transposed).
// EPI==1: bias add -> Cout [M][1024] f32.  APLANE: A is plane layout.
// ---------------------------------------------------------------------------
template <int EPI, bool APLANE>
__global__ __launch_bounds__(256) void gemm_lds(
    const bf16* __restrict__ A, const bf16* __restrict__ W,
    const float* __restrict__ bias,
    bf16* __restrict__ q_ws, bf16* __restrict__ k_ws, bf16* __restrict__ vt_ws,
    float* __restrict__ Cout, int K) {
  __shared__ __align__(16) bf16 Als[128 * 32];
  __shared__ __align__(16) bf16 Bls[128 * 32];
  const int m0 = blockIdx.y * 128;
  const int n0 = blockIdx.x * 128;
  const int tid = threadIdx.x;
  const int w = tid >> 6;
  const int lane = tid & 63;
  const int lx = lane & 15;
  const int quad = lane >> 4;
  const int amb = (w & 1) * 64;
  const int bnb = (w >> 1) * 64;

  f32x4 acc[4][4];
#pragma unroll
  for (int i = 0; i < 4; i++)
#pragma unroll
    for (int j = 0; j < 4; j++) acc[i][j] = (f32x4){0.f, 0.f, 0.f, 0.f};

  for (int k0 = 0; k0 < K; k0 += 32) {
    __syncthreads();
#pragma unroll
    for (int i = 0; i < 2; i++) {
      int chunk = i * 256 + tid;
      int row = chunk >> 2, seg = chunk & 3;
      const bf16* ga;
      if constexpr (APLANE) {
        int c0 = k0 + seg * 8;
        int m = m0 + row;
        ga = A + ((size_t)((m >> 11) * H_ + (c0 >> 6)) * T_ + (m & 2047)) *
                     HD_ + (c0 & 63);
      } else {
        ga = A + (size_t)(m0 + row) * K + k0 + seg * 8;
      }
      gl_lds16(ga, &Als[i * 2048 + w * 512]);
      gl_lds16(W + (size_t)(n0 + row) * K + k0 + seg * 8,
               &Bls[i * 2048 + w * 512]);
    }
    __syncthreads();

    bf16x8 af[4], bfr[4];
#pragma unroll
    for (int mt = 0; mt < 4; mt++)
      af[mt] = *(const bf16x8*)&Als[(amb + mt * 16 + lx) * 32 + quad * 8];
#pragma unroll
    for (int nt = 0; nt < 4; nt++)
      bfr[nt] = *(const bf16x8*)&Bls[(bnb + nt * 16 + lx) * 32 + quad * 8];
#pragma unroll
    for (int mt = 0; mt < 4; mt++)
#pragma unroll
      for (int nt = 0; nt < 4; nt++)
        acc[mt][nt] = mfma16(af[mt], bfr[nt], acc[mt][nt]);
  }

  if (EPI == 0) {
#pragma unroll
    for (int mt = 0; mt < 4; mt++) {
      int mbase = m0 + amb + mt * 16 + quad * 4;
      int b = mbase >> 11;
      int t = mbase & 2047;
#pragma unroll
      for (int nt = 0; nt < 4; nt++) {
        int col = n0 + bnb + nt * 16 + lx;
        int which = col >> 10;
        int d = col & 1023;
        int h = d >> 6, hdi = d & 63;
        int bh = b * H_ + h;
        if (which == 0) {
#pragma unroll
          for (int r = 0; r < 4; r++)
            q_ws[((size_t)bh * T_ + t + r) * HD_ + hdi] = (bf16)acc[mt][nt][r];
        } else if (which == 1) {
#pragma unroll
          for (int r = 0; r < 4; r++)
            k_ws[((size_t)bh * T_ + t + r) * HD_ + hdi] = (bf16)acc[mt][nt][r];
        } else {
          *(ushort4*)&vt_ws[((size_t)bh * HD_ + hdi) * T_ + t] =
              pack4(acc[mt][nt]);
        }
      }
    }
  } else {
#pragma unroll
    for (int nt = 0; nt < 4; nt++) {
      int col = n0 + bnb + nt * 16 + lx;
      float bias_f = bias[col];
#pragma unroll
      for (int mt = 0; mt < 4; mt++) {
        int mbase = m0 + amb + mt * 16 + quad * 4;
#pragma unroll
        for (int r = 0; r < 4; r++)
          Cout[(size_t)(mbase + r) * D_ + col] = acc[mt][nt][r] + bias_f;
      }
    }
  }
}

// ---------------------------------------------------------------------------
// Flash attention, split-KV x2, 256-q blocks (4 q-groups/wave).
// grid 512: bh = blk&31 (XCD-local), qt = (blk>>5)&7, half = blk>>8.
// Per iter: stage K/V 64-kv tile once; ka (8 b128) and va (16 b64) fragments
// loaded from LDS ONCE into registers and reused across all 4 q-groups ->
// per-element LDS/staging cost halves vs 128-q blocks.
// No max-subtraction -> partials are plain sums (additive merge).
// ---------------------------------------------------------------------------
__global__ __launch_bounds__(256, 2) void attn_kernel(
    const bf16* __restrict__ q_ws, const bf16* __restrict__ k_ws,
    const bf16* __restrict__ vt_ws, const bf16* __restrict__ mem_k,
    const bf16* __restrict__ mem_vt, bf16* __restrict__ opart,
    float* __restrict__ lpart) {
  __shared__ __align__(16) bf16 Kls[64][72];
  __shared__ __align__(16) bf16 Vls[64][72];
  const int tid = threadIdx.x;
  const int w = tid >> 6;
  const int lane = tid & 63;
  const int lx = lane & 15;
  const int quad = lane >> 4;
  const int bh = blockIdx.x & 31;
  const int qt = (blockIdx.x >> 5) & 7;
  const int half = blockIdx.x >> 8;
  const int q0 = qt * 256 + w * 64;
  const int h = bh & 15;

  const int srow1 = tid >> 3, soff1 = (tid & 7) * 8;
  const int srow2 = (tid + 256) >> 3, soff2 = soff1;

  const bf16* qbase = q_ws + ((size_t)bh * T_ + q0) * HD_;

  // Q B-frags (k32), 4 q-groups of 16
  bf16x8 qf[4][2];
#pragma unroll
  for (int qg = 0; qg < 4; qg++)
#pragma unroll
    for (int hf = 0; hf < 2; hf++) {
      bf16x8 v = *(const bf16x8*)(qbase + (size_t)(qg * 16 + lx) * HD_ +
                                  hf * 32 + quad * 8);
#pragma unroll
      for (int i = 0; i < 8; i++)
        v[i] = (bf16)((float)v[i] * 0.125f);   // fold scale (exact pow2)
      qf[qg][hf] = v;
    }

  const bf16* kplane = k_ws + (size_t)bh * T_ * HD_;
  const bf16* vtplane = vt_ws + (size_t)bh * HD_ * T_;
  const bf16* mkh = mem_k + h * HD_;
  const bf16* mvh = mem_vt + (size_t)h * HD_ * MEM_;

  f32x4 o[4][4];   // [mt][qg]
#pragma unroll
  for (int mt = 0; mt < 4; mt++)
#pragma unroll
    for (int qg = 0; qg < 4; qg++) o[mt][qg] = (f32x4){0.f, 0.f, 0.f, 0.f};
  float lsum[4] = {0.f, 0.f, 0.f, 0.f};

  const int it0 = half * HITER;
  for (int it = it0; it < it0 + HITER; it++) {
    const int kv0 = it * 64;
    const bool memPart = kv0 < MEM_;
    bf16x8 kr1, kr2, vr1, vr2;
    if (memPart) {
      kr1 = *(const bf16x8*)(mkh + (size_t)(kv0 + srow1) * D_ + soff1);
      kr2 = *(const bf16x8*)(mkh + (size_t)(kv0 + srow2) * D_ + soff2);
      vr1 = *(const bf16x8*)(mvh + (size_t)srow1 * MEM_ + kv0 + soff1);
      vr2 = *(const bf16x8*)(mvh + (size_t)srow2 * MEM_ + kv0 + soff2);
    } else {
      const int t0 = kv0 - MEM_;
      kr1 = *(const bf16x8*)(kplane + (size_t)(t0 + srow1) * HD_ + soff1);
      kr2 = *(const bf16x8*)(kplane + (size_t)(t0 + srow2) * HD_ + soff2);
      vr1 = *(const bf16x8*)(vtplane + (size_t)srow1 * T_ + t0 + soff1);
      vr2 = *(const bf16x8*)(vtplane + (size_t)srow2 * T_ + t0 + soff2);
    }
    __syncthreads();
    *(bf16x8*)&Kls[srow1][soff1] = kr1;
    *(bf16x8*)&Kls[srow2][soff2] = kr2;
    *(bf16x8*)&Vls[srow1][soff1] = vr1;
    *(bf16x8*)&Vls[srow2][soff2] = vr2;
    __syncthreads();

    // fragment loads ONCE; reused across 4 q-groups
    bf16x8 ka[4][2];
#pragma unroll
    for (int g = 0; g < 4; g++) {
      ka[g][0] = *(const bf16x8*)&Kls[g * 16 + lx][quad * 8];
      ka[g][1] = *(const bf16x8*)&Kls[g * 16 + lx][32 + quad * 8];
    }
    s16x4 va[4][4];
#pragma unroll
    for (int mt = 0; mt < 4; mt++)
#pragma unroll
      for (int kk = 0; kk < 4; kk++)
        va[mt][kk] = *(const s16x4*)&Vls[mt * 16 + lx][kk * 16 + quad * 4];

#pragma unroll
    for (int qg = 0; qg < 4; qg++) {
      f32x4 s[4];
#pragma unroll
      for (int g = 0; g < 4; g++) {
        s[g] = (f32x4){0.f, 0.f, 0.f, 0.f};
        s[g] = mfma16(ka[g][0], qf[qg][0], s[g]);
        s[g] = mfma16(ka[g][1], qf[qg][1], s[g]);
      }
      s16x4 pb[4];
      float ps = 0.f;
#pragma unroll
      for (int g = 0; g < 4; g++) {
#pragma unroll
        for (int r = 0; r < 4; r++) {
          float p = __expf(s[g][r]);
          ps += p;
          pb[g][r] = (short)bf16_bits(p);
        }
      }
      lsum[qg] += ps;
#pragma unroll
      for (int mt = 0; mt < 4; mt++)
#pragma unroll
        for (int kk = 0; kk < 4; kk++)
          o[mt][qg] = mfma16k16(va[mt][kk], pb[kk], o[mt][qg]);
    }
  }

  // partial row sums: quad-reduce, lanes of quad 0 store (one per q row)
#pragma unroll
  for (int qg = 0; qg < 4; qg++) {
    float s2 = lsum[qg];
    s2 += __shfl_xor(s2, 16);
    s2 += __shfl_xor(s2, 32);
    if (quad == 0)
      lpart[(size_t)half * 65536 + (size_t)bh * T_ + q0 + qg * 16 + lx] = s2;
  }

  // partial O (unnormalized) -> opart[half] in plane layout [bh][t][64]
  bf16* obase = opart + (size_t)half * 4194304 + ((size_t)bh * T_ + q0) * HD_;
#pragma unroll
  for (int qg = 0; qg < 4; qg++)
#pragma unroll
    for (int mt = 0; mt < 4; mt++)
      *(ushort4*)(obase + (size_t)(qg * 16 + lx) * HD_ + mt * 16 + quad * 4) =
          pack4(o[mt][qg]);
}

// ---------------------------------------------------------------------------
// merge: q_ws[i] = (O0[i]+O1[i]) / (l0[row]+l1[row]);  8 elems/thread.
// ---------------------------------------------------------------------------
__global__ void merge_kernel(const bf16* __restrict__ opart,
                             const float* __restrict__ lpart,
                             bf16* __restrict__ q_ws) {
  size_t i8 = ((size_t)blockIdx.x * 256 + threadIdx.x) * 8;   // [0, 4M)
  size_t row = i8 >> 6;
  float inv = 1.f / (lpart[row] + lpart[65536 + row]);
  bf16x8 a = *(const bf16x8*)(opart + i8);
  bf16x8 b = *(const bf16x8*)(opart + 4194304 + i8);
  bf16x8 r;
#pragma unroll
  for (int j = 0; j < 8; j++)
    r[j] = (bf16)(((float)a[j] + (float)b[j]) * inv);
  *(bf16x8*)(q_ws + i8) = r;
}

// ---------------------------------------------------------------------------
extern "C" void kernel_launch(void* const* d_in, const int* in_sizes, int n_in,
                              void* d_out, int out_size, void* d_ws,
                              size_t ws_size, hipStream_t stream) {
  const float* x      = (const float*)d_in[0];   // [B,T,D]
  const float* w_qkv  = (const float*)d_in[1];   // [3D,D]
  const float* w_out  = (const float*)d_in[2];   // [D,D]
  const float* b_out  = (const float*)d_in[3];   // [D]
  const float* memory = (const float*)d_in[4];   // [MEM,D]

  // ws (28.5 MiB used):
  char* ws = (char*)d_ws;
  bf16* q_ws   = (bf16*)(ws);                    // [32][2048][64]  8 MiB
  bf16* k_ws   = (bf16*)(ws + (8u << 20));       // [32][2048][64]  8 MiB
  bf16* vt_ws  = (bf16*)(ws + (16u << 20));      // [32][64][2048]  8 MiB
  bf16* mem_k  = (bf16*)(ws + (24u << 20));      // [512][1024]     1 MiB
  bf16* mem_vt = (bf16*)(ws + (25u << 20));      // [1024][512]     1 MiB
  bf16* wob    = (bf16*)(ws + (26u << 20));      // [1024][1024]    2 MiB
  float* lpart = (float*)(ws + (28u << 20));     // [2][65536]    0.5 MiB
  // d_out (16 MiB f32) as phased scratch: xb/wqb (conv+qkv), then attn
  // partials O0/O1, finally the real f32 output.
  char* outc = (char*)d_out;
  bf16* xb    = (bf16*)(outc);                   // [4096][1024]    8 MiB
  bf16* wqb   = (bf16*)(outc + (8u << 20));      // [3072][1024]    6 MiB
  bf16* opart = (bf16*)(outc);                   // [2][4M]        16 MiB
  float* out = (float*)d_out;

  convert_all<<<dim3(8704), dim3(256), 0, stream>>>(
      x, w_qkv, w_out, memory, xb, wqb, wob, mem_k, mem_vt);
  gemm_lds<0, false><<<dim3(24, 32), dim3(256), 0, stream>>>(
      xb, wqb, nullptr, q_ws, k_ws, vt_ws, nullptr, 1024);
  attn_kernel<<<dim3(512), dim3(256), 0, stream>>>(
      q_ws, k_ws, vt_ws, mem_k, mem_vt, opart, lpart);
  merge_kernel<<<dim3(2048), dim3(256), 0, stream>>>(opart, lpart, q_ws);
  gemm_lds<1, true><<<dim3(8, 32), dim3(256), 0, stream>>>(
      q_ws, wob, b_out, nullptr, nullptr, nullptr, out, 1024);
}

// Round 14
// 222.862 us; speedup vs baseline: 1.0286x; 1.0286x over previous
//
#include <hip/hip_runtime.h>
#include <hip/hip_bf16.h>
#include <stdint.h>

// Problem constants
#define B_   2
#define T_   2048
#define D_   1024
#define H_   16
#define HD_  64
#define MEM_ 512
#define KV_  (MEM_ + T_)   // 2560
#define NIT_ (KV_ / 64)    // 40 kv-tiles of 64

using bf16 = __bf16;
typedef __bf16 bf16x8 __attribute__((ext_vector_type(8)));
typedef float  f32x4  __attribute__((ext_vector_type(4)));
typedef short  s16x4  __attribute__((ext_vector_type(4)));

__device__ __forceinline__ f32x4 mfma16(bf16x8 a, bf16x8 b, f32x4 c) {
  return __builtin_amdgcn_mfma_f32_16x16x32_bf16(a, b, c, 0, 0, 0);
}
__device__ __forceinline__ f32x4 mfma16k16(s16x4 a, s16x4 b, f32x4 c) {
  return __builtin_amdgcn_mfma_f32_16x16x16bf16_1k(a, b, c, 0, 0, 0);
}

// Load 8 consecutive elements at element-offset `off`; f32 path converts.
template <bool F32>
__device__ __forceinline__ bf16x8 load8(const void* p, size_t off) {
  if constexpr (F32) {
    const float* q = (const float*)p + off;
    f32x4 u = *(const f32x4*)q;
    f32x4 v = *(const f32x4*)(q + 4);
    bf16x8 r;
    r[0] = (bf16)u[0]; r[1] = (bf16)u[1]; r[2] = (bf16)u[2]; r[3] = (bf16)u[3];
    r[4] = (bf16)v[0]; r[5] = (bf16)v[1]; r[6] = (bf16)v[2]; r[7] = (bf16)v[3];
    return r;
  } else {
    return *(const bf16x8*)((const bf16*)p + off);
  }
}

__device__ __forceinline__ unsigned short bf16_bits(float f) {
  bf16 h = (bf16)f;
  return __builtin_bit_cast(unsigned short, h);
}

__device__ __forceinline__ ushort4 pack4(f32x4 v) {
  ushort4 p;
  p.x = bf16_bits(v[0]); p.y = bf16_bits(v[1]);
  p.z = bf16_bits(v[2]); p.w = bf16_bits(v[3]);
  return p;
}

// ---------------------------------------------------------------------------
// fill: memory [512][1024] f32 -> mem_k bf16 (same layout) and
//       mem_vt bf16 [1024][512] (transposed).
// ---------------------------------------------------------------------------
__global__ void fill_mem(const float* __restrict__ memory,
                         bf16* __restrict__ mem_k, bf16* __restrict__ mem_vt) {
  int idx = blockIdx.x * 256 + threadIdx.x;   // [0, 512*1024)
  int m = idx >> 10, d = idx & 1023;
  bf16 v = (bf16)memory[idx];
  mem_k[idx] = v;
  mem_vt[(size_t)d * MEM_ + m] = v;
}

// ---------------------------------------------------------------------------
// GEMM (B^T form): C[M,N] = A[M,K] * W[N,K]^T.  128x128 tile, BK=32,
// 4 waves (2x2 of 64x64), register-staged LDS (f32 inputs converted to bf16
// in flight - the R5-measured fastest configuration for these shapes).
// EPI==0: scatter q/k -> [bh][t][64], v -> vt_ws[bh][hd][t] (transposed).
// EPI==1: bias add -> Cout [M][1024] f32.  APLANE: A is plane layout
//         [bh][t][64] (logical row m=b*T+t, col d=h*64+hd).
// ---------------------------------------------------------------------------
template <int EPI, bool AF32, bool WF32, bool APLANE>
__global__ __launch_bounds__(256) void gemm_bt(
    const void* __restrict__ A, const void* __restrict__ W,
    const float* __restrict__ bias,
    bf16* __restrict__ q_ws, bf16* __restrict__ k_ws, bf16* __restrict__ vt_ws,
    float* __restrict__ Cout, int K) {
  __shared__ __align__(16) bf16 Als[128 * 32];
  __shared__ __align__(16) bf16 Bls[128 * 32];
  const int m0 = blockIdx.y * 128;
  const int n0 = blockIdx.x * 128;
  const int tid = threadIdx.x;
  const int w = tid >> 6;
  const int lane = tid & 63;
  const int lx = lane & 15;
  const int quad = lane >> 4;
  const int amb = (w & 1) * 64;
  const int bnb = (w >> 1) * 64;
  const int r0 = tid >> 2, seg = tid & 3;   // staging coords

  f32x4 acc[4][4];
#pragma unroll
  for (int i = 0; i < 4; i++)
#pragma unroll
    for (int j = 0; j < 4; j++) acc[i][j] = (f32x4){0.f, 0.f, 0.f, 0.f};

  for (int k0 = 0; k0 < K; k0 += 32) {
    bf16x8 a0, a1;
    if constexpr (APLANE) {
      // row m -> (b,t); col chunk k0+seg*8 (within one h, since 32 | 64)
      int c0 = k0 + seg * 8, h = c0 >> 6, hd = c0 & 63;
      int mA = m0 + r0, mB = m0 + 64 + r0;
      a0 = load8<false>(A,
          ((size_t)((mA >> 11) * H_ + h) * T_ + (mA & 2047)) * HD_ + hd);
      a1 = load8<false>(A,
          ((size_t)((mB >> 11) * H_ + h) * T_ + (mB & 2047)) * HD_ + hd);
    } else {
      a0 = load8<AF32>(A, (size_t)(m0 + r0) * K + k0 + seg * 8);
      a1 = load8<AF32>(A, (size_t)(m0 + 64 + r0) * K + k0 + seg * 8);
    }
    bf16x8 b0 = load8<WF32>(W, (size_t)(n0 + r0) * K + k0 + seg * 8);
    bf16x8 b1 = load8<WF32>(W, (size_t)(n0 + 64 + r0) * K + k0 + seg * 8);
    __syncthreads();   // prev iteration's LDS reads done
    *(bf16x8*)&Als[tid * 8] = a0;          // row-major [128][32]
    *(bf16x8*)&Als[2048 + tid * 8] = a1;
    *(bf16x8*)&Bls[tid * 8] = b0;
    *(bf16x8*)&Bls[2048 + tid * 8] = b1;
    __syncthreads();   // tiles valid

    bf16x8 af[4], bfr[4];
#pragma unroll
    for (int mt = 0; mt < 4; mt++)
      af[mt] = *(const bf16x8*)&Als[(amb + mt * 16 + lx) * 32 + quad * 8];
#pragma unroll
    for (int nt = 0; nt < 4; nt++)
      bfr[nt] = *(const bf16x8*)&Bls[(bnb + nt * 16 + lx) * 32 + quad * 8];
#pragma unroll
    for (int mt = 0; mt < 4; mt++)
#pragma unroll
      for (int nt = 0; nt < 4; nt++)
        acc[mt][nt] = mfma16(af[mt], bfr[nt], acc[mt][nt]);
  }

  // Epilogue. C/D layout: row = quad*4+reg (m), col = lane&15 (n).
  if (EPI == 0) {
#pragma unroll
    for (int mt = 0; mt < 4; mt++) {
      int mbase = m0 + amb + mt * 16 + quad * 4;
      int b = mbase >> 11;        // T=2048
      int t = mbase & 2047;
#pragma unroll
      for (int nt = 0; nt < 4; nt++) {
        int col = n0 + bnb + nt * 16 + lx;     // [0,3072)
        int which = col >> 10;                 // 0=q 1=k 2=v
        int d = col & 1023;
        int h = d >> 6, hdi = d & 63;
        int bh = b * H_ + h;
        if (which == 0) {
#pragma unroll
          for (int r = 0; r < 4; r++)
            q_ws[((size_t)bh * T_ + t + r) * HD_ + hdi] = (bf16)acc[mt][nt][r];
        } else if (which == 1) {
#pragma unroll
          for (int r = 0; r < 4; r++)
            k_ws[((size_t)bh * T_ + t + r) * HD_ + hdi] = (bf16)acc[mt][nt][r];
        } else {
          // v^T: 4 consecutive t -> one 8B store
          *(ushort4*)&vt_ws[((size_t)bh * HD_ + hdi) * T_ + t] =
              pack4(acc[mt][nt]);
        }
      }
    }
  } else {
#pragma unroll
    for (int nt = 0; nt < 4; nt++) {
      int col = n0 + bnb + nt * 16 + lx;
      float bias_f = bias[col];
#pragma unroll
      for (int mt = 0; mt < 4; mt++) {
        int mbase = m0 + amb + mt * 16 + quad * 4;
#pragma unroll
        for (int r = 0; r < 4; r++)
          Cout[(size_t)(mbase + r) * D_ + col] = acc[mt][nt][r] + bias_f;
      }
    }
  }
}

// ---------------------------------------------------------------------------
// Flash attention, LDS-staged + transpose trick (R10 proven structure) with
// the exp2 diet: Q pre-scaled by 0.125*log2(e) so p = exp2(s) is a single
// native v_exp_f32 (no per-element ln2 mul).
// 1 block = 128 q of one (b,h); 4 waves x 32 q; kv-tile 64; grid 512.
// Output written in place into q_ws (block owns its 128 q rows).
// ---------------------------------------------------------------------------
__global__ __launch_bounds__(256, 2) void attn_kernel(
    bf16* __restrict__ q_ws, const bf16* __restrict__ k_ws,
    const bf16* __restrict__ vt_ws, const bf16* __restrict__ mem_k,
    const bf16* __restrict__ mem_vt) {
  __shared__ __align__(16) bf16 Kls[64][72];
  __shared__ __align__(16) bf16 Vls[64][72];
  const int tid = threadIdx.x;
  const int w = tid >> 6;
  const int lane = tid & 63;
  const int lx = lane & 15;
  const int quad = lane >> 4;
  const int bh = blockIdx.x & 31;      // XCD-locality
  const int qt = blockIdx.x >> 5;      // 16 q-tiles of 128
  const int q0 = qt * 128 + w * 32;
  const int h = bh & 15;

  const int srow1 = tid >> 3, soff1 = (tid & 7) * 8;
  const int srow2 = (tid + 256) >> 3, soff2 = soff1;

  bf16* qbase = q_ws + ((size_t)bh * T_ + q0) * HD_;

  // Q B-frags (k32); fold softmax scale AND log2(e) into Q:
  // s = (q*0.125*log2e) . k  ->  exp2(s) == exp(0.125 * q.k)
  const float QSCALE = 0.125f * 1.44269504089f;
  bf16x8 qf[2][2];
#pragma unroll
  for (int qg = 0; qg < 2; qg++)
#pragma unroll
    for (int hf = 0; hf < 2; hf++) {
      bf16x8 v = *(const bf16x8*)(qbase + (size_t)(qg * 16 + lx) * HD_ +
                                  hf * 32 + quad * 8);
#pragma unroll
      for (int i = 0; i < 8; i++)
        v[i] = (bf16)((float)v[i] * QSCALE);
      qf[qg][hf] = v;
    }

  const bf16* kplane = k_ws + (size_t)bh * T_ * HD_;
  const bf16* vtplane = vt_ws + (size_t)bh * HD_ * T_;
  const bf16* mkh = mem_k + h * HD_;
  const bf16* mvh = mem_vt + (size_t)h * HD_ * MEM_;

  f32x4 o[4][2];
#pragma unroll
  for (int mt = 0; mt < 4; mt++)
#pragma unroll
    for (int qg = 0; qg < 2; qg++) o[mt][qg] = (f32x4){0.f, 0.f, 0.f, 0.f};
  float lsum[2] = {0.f, 0.f};

  for (int it = 0; it < NIT_; it++) {
    const int kv0 = it * 64;
    const bool memPart = kv0 < MEM_;
    bf16x8 kr1, kr2, vr1, vr2;
    if (memPart) {
      kr1 = *(const bf16x8*)(mkh + (size_t)(kv0 + srow1) * D_ + soff1);
      kr2 = *(const bf16x8*)(mkh + (size_t)(kv0 + srow2) * D_ + soff2);
      vr1 = *(const bf16x8*)(mvh + (size_t)srow1 * MEM_ + kv0 + soff1);
      vr2 = *(const bf16x8*)(mvh + (size_t)srow2 * MEM_ + kv0 + soff2);
    } else {
      const int t0 = kv0 - MEM_;
      kr1 = *(const bf16x8*)(kplane + (size_t)(t0 + srow1) * HD_ + soff1);
      kr2 = *(const bf16x8*)(kplane + (size_t)(t0 + srow2) * HD_ + soff2);
      vr1 = *(const bf16x8*)(vtplane + (size_t)srow1 * T_ + t0 + soff1);
      vr2 = *(const bf16x8*)(vtplane + (size_t)srow2 * T_ + t0 + soff2);
    }
    __syncthreads();
    *(bf16x8*)&Kls[srow1][soff1] = kr1;
    *(bf16x8*)&Kls[srow2][soff2] = kr2;
    *(bf16x8*)&Vls[srow1][soff1] = vr1;
    *(bf16x8*)&Vls[srow2][soff2] = vr2;
    __syncthreads();

    f32x4 s[4][2];
#pragma unroll
    for (int g = 0; g < 4; g++) {
      bf16x8 ka0 = *(const bf16x8*)&Kls[g * 16 + lx][quad * 8];
      bf16x8 ka1 = *(const bf16x8*)&Kls[g * 16 + lx][32 + quad * 8];
#pragma unroll
      for (int qg = 0; qg < 2; qg++) {
        s[g][qg] = (f32x4){0.f, 0.f, 0.f, 0.f};
        s[g][qg] = mfma16(ka0, qf[qg][0], s[g][qg]);
        s[g][qg] = mfma16(ka1, qf[qg][1], s[g][qg]);
      }
    }

    s16x4 pb[2][4];
#pragma unroll
    for (int qg = 0; qg < 2; qg++) {
      float ps = 0.f;
#pragma unroll
      for (int g = 0; g < 4; g++) {
#pragma unroll
        for (int r = 0; r < 4; r++) {
          float p = __builtin_amdgcn_exp2f(s[g][qg][r]);  // raw v_exp_f32
          ps += p;
          pb[qg][g][r] = (short)bf16_bits(p);
        }
      }
      lsum[qg] += ps;
    }

#pragma unroll
    for (int mt = 0; mt < 4; mt++) {
#pragma unroll
      for (int kk = 0; kk < 4; kk++) {
        s16x4 va = *(const s16x4*)&Vls[mt * 16 + lx][kk * 16 + quad * 4];
#pragma unroll
        for (int qg = 0; qg < 2; qg++)
          o[mt][qg] = mfma16k16(va, pb[qg][kk], o[mt][qg]);
      }
    }
  }

  float inv[2];
#pragma unroll
  for (int qg = 0; qg < 2; qg++) {
    float s2 = lsum[qg];
    s2 += __shfl_xor(s2, 16);
    s2 += __shfl_xor(s2, 32);
    inv[qg] = 1.f / s2;
  }

#pragma unroll
  for (int qg = 0; qg < 2; qg++) {
#pragma unroll
    for (int mt = 0; mt < 4; mt++) {
      f32x4 ov;
#pragma unroll
      for (int r = 0; r < 4; r++) ov[r] = o[mt][qg][r] * inv[qg];
      *(ushort4*)(qbase + (size_t)(qg * 16 + lx) * HD_ + mt * 16 + quad * 4)
          = pack4(ov);
    }
  }
}

// ---------------------------------------------------------------------------
extern "C" void kernel_launch(void* const* d_in, const int* in_sizes, int n_in,
                              void* d_out, int out_size, void* d_ws,
                              size_t ws_size, hipStream_t stream) {
  const void*  x      = d_in[0];                 // [B,T,D]   f32
  const void*  w_qkv  = d_in[1];                 // [3D,D]    f32
  const void*  w_out  = d_in[2];                 // [D,D]     f32
  const float* b_out  = (const float*)d_in[3];   // [D]       f32
  const float* memory = (const float*)d_in[4];   // [MEM,D]   f32

  char* ws = (char*)d_ws;
  bf16* q_ws   = (bf16*)(ws);                    // [32][2048][64]  8 MiB
  bf16* k_ws   = (bf16*)(ws + (8u << 20));       // [32][2048][64]  8 MiB
  bf16* vt_ws  = (bf16*)(ws + (16u << 20));      // [32][64][2048]  8 MiB
  bf16* mem_k  = (bf16*)(ws + (24u << 20));      // [512][1024]     1 MiB
  bf16* mem_vt = (bf16*)(ws + (25u << 20));      // [1024][512]     1 MiB
  float* out = (float*)d_out;                    // f32 per reference

  fill_mem<<<dim3(2048), dim3(256), 0, stream>>>(memory, mem_k, mem_vt);
  gemm_bt<0, true, true, false><<<dim3(24, 32), dim3(256), 0, stream>>>(
      x, w_qkv, nullptr, q_ws, k_ws, vt_ws, nullptr, 1024);
  attn_kernel<<<dim3(512), dim3(256), 0, stream>>>(
      q_ws, k_ws, vt_ws, mem_k, mem_vt);
  gemm_bt<1, false, true, true><<<dim3(8, 32), dim3(256), 0, stream>>>(
      q_ws, w_out, b_out, nullptr, nullptr, nullptr, out, 1024);
}